// Round 11
// baseline (492.508 us; speedup 1.0000x reference)
//
#include <hip/hip_runtime.h>
#include <hip/hip_bf16.h>
#include <cstdint>

// ---------------------------------------------------------------------------
// TransformerClassifier: 2x single-head attention (N=4, L=2048, D=1024) +
// mean-pool + linear + sigmoid.
//
// v9 = v8 (pure bf16, proven m97-style GEMM) + algebraic work elimination:
//   * PV-2 + mean-pool collapsed:  pooled = (1/L)(1^T P2) V2  -> colsum(P2)
//     then a tiny matvec against V^T.  Deletes PV-2 GEMM, H2 (32MB fp32),
//     and pool_partial.  Exact (sum reordering only).
//   * Q/K/V projections fused into ONE GEMM with concatenated weights
//     (N=3072); per-block-uniform epilogue routes Q/K row-major and V
//     transposed.  X read once per layer instead of 3x.
//   * 6 weight transposes batched into one launch (grid z=6).
//
// GEMM: 128x128 tile, BK=32, 256 thr (4 waves, 64x64), double-buffered LDS
// (16KB/buf), ONE __syncthreads per K-tile, global_load_lds staging with
// pre-swizzled global sources; A/B rows = 4x16B slots,
// slot = chunk ^ ((row>>1)&3)  (conflict-free, verified R9/R10).
//
// ws layout (216 MB):
//   [  0MB) Xb    : X bf16; overwritten by H1 bf16        (16 MB)
//   [ 32MB) Qb    : Q bf16                                 (16 MB)
//   [ 64MB) Kb    : K bf16                                 (16 MB)
//   [ 80MB) partial/colsum scratch                         (<1 MB)
//   [ 96MB) Vtb   : V^T bf16 (per-batch [d][l])            (16 MB)
//   [128MB) Wcat  : 2 layers x (3072x1024) W^T bf16        (12 MB)
//   [152MB) S/P   : scores fp32 -> P bf16 in place         (64 MB)
// ---------------------------------------------------------------------------

#define DEVFN __device__ __forceinline__

typedef __attribute__((ext_vector_type(8))) short bf16x8;
typedef __attribute__((ext_vector_type(4))) float f32x4;
typedef unsigned short u16;

DEVFN u16 f2bf(float f) {               // round-to-nearest-even bf16 (finite)
    uint32_t x = __float_as_uint(f);
    x += 0x7fffu + ((x >> 16) & 1u);
    return (u16)(x >> 16);
}
DEVFN float bf2f(u16 u) { return __uint_as_float(((uint32_t)u) << 16); }

DEVFN void gload_lds16(const void* g, void* l) {
    __builtin_amdgcn_global_load_lds(
        (const __attribute__((address_space(1))) void*)g,
        (__attribute__((address_space(3))) void*)l, 16, 0, 0);
}

#define MFMA16 __builtin_amdgcn_mfma_f32_16x16x32_bf16

// ---------------------------------------------------------------------------
// bf16 GEMM:  C = scale * (A . B^T)
//   A : M x K row-major bf16 (lda);  B : N x K row-major bf16 (ldb)
// Tile 128x128, BK=32.  Requires M%128==0, N%128==0, K%32==0, K/32>=2,
// grid (N/128, M/128, Z), total blocks % 8 == 0.
// EPI: 1 = fp32 row-major (out0)
//      3 = bf16 row-major (out0)
//      4 = fused-QKV routing: N=3072; seg 0 -> out0 (Q, row-major),
//          seg 1 -> out1 (K, row-major), seg 2 -> out2 (V^T per-batch)
// ---------------------------------------------------------------------------
template<int EPI>
__global__ __launch_bounds__(256, 4) void gemmk(
    const u16* __restrict__ A, long long aStride,
    const u16* __restrict__ B, long long bStride,
    void* __restrict__ out0, void* __restrict__ out1, void* __restrict__ out2,
    long long cStride,
    int M, int N, int K, int lda, int ldb, int ldc, float scale)
{
    constexpr int ASEC  = 128 * 32;          // u16 per buffer, A section
    constexpr int BUFSZ = ASEC + 128 * 32;   // + B section
    constexpr int NU    = 4;                 // stage units (A:2, B:2)

    __shared__ __align__(16) u16 L[2 * BUFSZ];
    const int tid  = threadIdx.x;
    const int wave = tid >> 6, lane = tid & 63;

    // bijective XCD-aware block swizzle (all launches have nwg % 8 == 0)
    const int gx = gridDim.x, gy = gridDim.y;
    const int nwg = gx * gy * gridDim.z;
    int flat = (blockIdx.z * gy + blockIdx.y) * gx + blockIdx.x;
    flat = (flat & 7) * (nwg >> 3) + (flat >> 3);
    const int bx = flat % gx, by = (flat / gx) % gy, bz = flat / (gx * gy);

    const u16* pA = A + (size_t)bz * aStride;
    const u16* pB = B + (size_t)bz * bStride;
    const int m0 = by * 128, n0 = bx * 128;

    // ---- staging units: each = 2048 u16 (256 thr x 16B), linear LDS dest;
    // 4 slots/row, stored chunk = slot ^ ((row>>1)&3)  (pre-swizzled source)
    const u16* src[NU];
    int dst[NU];
#pragma unroll
    for (int q = 0; q < 2; q++) {
        const int s = q * 256 + tid, row = s >> 2, c = (s & 3) ^ ((row >> 1) & 3);
        src[q]     = pA + (size_t)(m0 + row) * lda + c * 8;
        dst[q]     = q * 2048 + wave * 512;
        src[2 + q] = pB + (size_t)(n0 + row) * ldb + c * 8;
        dst[2 + q] = ASEC + q * 2048 + wave * 512;
    }

    // ---- fragment geometry (16x16 frags; wave = 64x64 quadrant)
    const int fr = lane & 15, ch = lane >> 4;
    const int wr = (wave >> 1) * 64, wc = (wave & 1) * 64;

    const int NT = K >> 5;

    // ---- prologue: stage tile 0 into buffer 0
#pragma unroll
    for (int u = 0; u < NU; u++) { gload_lds16(src[u], &L[dst[u]]); src[u] += 32; }
    __syncthreads();

    f32x4 acc[4][4] = {};
    int cur = 0;

    for (int kt = 0; kt < NT; ++kt) {
        const int cOff = cur * BUFSZ;
        const int sOff = BUFSZ - cOff;
        if (kt + 1 < NT) {
#pragma unroll
            for (int u = 0; u < NU; u++) { gload_lds16(src[u], &L[sOff + dst[u]]); src[u] += 32; }
        }

        bf16x8 ah[4], bh[4];
#pragma unroll
        for (int i = 0; i < 4; i++) {
            const int r = wr + i * 16 + fr;
            ah[i] = *(const bf16x8*)&L[cOff + r * 32 + ((ch ^ ((r >> 1) & 3)) << 3)];
        }
#pragma unroll
        for (int j = 0; j < 4; j++) {
            const int r = wc + j * 16 + fr;
            bh[j] = *(const bf16x8*)&L[cOff + ASEC + r * 32 + ((ch ^ ((r >> 1) & 3)) << 3)];
        }

#pragma unroll
        for (int i = 0; i < 4; i++)
#pragma unroll
            for (int j = 0; j < 4; j++)
                acc[i][j] = MFMA16(ah[i], bh[j], acc[i][j], 0, 0, 0);

        __syncthreads();     // drains vmcnt (staging) + lgkm; swap buffers
        cur ^= 1;
    }

    // ---- epilogue: C/D layout col = lane&15, row = (lane>>4)*4 + r
    const int seg = n0 >> 10;               // uniform per block (EPI 4)
#pragma unroll
    for (int i = 0; i < 4; i++)
#pragma unroll
        for (int j = 0; j < 4; j++)
#pragma unroll
            for (int r = 0; r < 4; r++) {
                const int row = m0 + wr + i * 16 + (lane >> 4) * 4 + r;
                const int col = n0 + wc + j * 16 + (lane & 15);
                const float v = acc[i][j][r] * scale;
                if constexpr (EPI == 1) {
                    ((float*)out0)[(size_t)bz * cStride + (size_t)row * ldc + col] = v;
                } else if constexpr (EPI == 3) {
                    ((u16*)out0)[(size_t)bz * cStride + (size_t)row * ldc + col] = f2bf(v);
                } else {  // EPI == 4: fused QKV routing
                    const int c = col & 1023;
                    if (seg == 0) {
                        ((u16*)out0)[(size_t)row * 1024 + c] = f2bf(v);
                    } else if (seg == 1) {
                        ((u16*)out1)[(size_t)row * 1024 + c] = f2bf(v);
                    } else {  // V^T per-batch: [b][d][l]
                        const int b = row >> 11, ll = row & 2047;
                        ((u16*)out2)[(size_t)b * (2048 * 1024) + (size_t)c * 2048 + ll] = f2bf(v);
                    }
                }
            }
}

// ---------------------------------------------------------------------------
__global__ __launch_bounds__(256) void cast_bf16(
    const float* __restrict__ x, u16* __restrict__ o)
{
    const size_t i = ((size_t)blockIdx.x * 256 + threadIdx.x) * 4;
    const float4 v = *(const float4*)&x[i];
    ushort4 h;
    h.x = f2bf(v.x); h.y = f2bf(v.y); h.z = f2bf(v.z); h.w = f2bf(v.w);
    *(ushort4*)&o[i] = h;
}

// ---------------------------------------------------------------------------
// Batched W -> W^T bf16 into concatenated per-layer buffers:
// Wcat layer L rows [0,1024)=W_Q^T, [1024,2048)=W_K^T, [2048,3072)=W_V^T
// grid (16, 16, 6)
// ---------------------------------------------------------------------------
__global__ __launch_bounds__(256) void transpose_cat(
    const float* __restrict__ W0, const float* __restrict__ W1,
    const float* __restrict__ W2, const float* __restrict__ W3,
    const float* __restrict__ W4, const float* __restrict__ W5,
    u16* __restrict__ Wcat)
{
    const int w = blockIdx.z;
    const float* W = (w == 0) ? W0 : (w == 1) ? W1 : (w == 2) ? W2
                   : (w == 3) ? W3 : (w == 4) ? W4 : W5;
    u16* dstb = Wcat + (size_t)(w / 3) * (3072 * 1024)
                     + (size_t)(w % 3) * (1024 * 1024);
    __shared__ float t[64][65];
    const int tid = threadIdx.x;
    const int r0 = blockIdx.y * 64, c0 = blockIdx.x * 64;
#pragma unroll
    for (int it = 0; it < 16; it++) {
        const int idx = it * 256 + tid, rr = idx >> 6, cc = idx & 63;
        t[rr][cc] = W[(size_t)(r0 + rr) * 1024 + (c0 + cc)];
    }
    __syncthreads();
#pragma unroll
    for (int it = 0; it < 16; it++) {
        const int idx = it * 256 + tid, nn = idx >> 6, kk = idx & 63;
        dstb[(size_t)(c0 + nn) * 1024 + (r0 + kk)] = f2bf(t[kk][nn]);
    }
}

// ---------------------------------------------------------------------------
// Row softmax over 2048 fp32 scores, written IN PLACE as P bf16 (row head)
// ---------------------------------------------------------------------------
__global__ __launch_bounds__(256) void softmax_rows(float* __restrict__ S)
{
    const int r   = blockIdx.x;                 // 0..8191 (batch*2048 + l)
    float* row    = S + (size_t)r * 2048;
    const int tid = threadIdx.x;

    const float4 a = *(const float4*)&row[tid * 8];
    const float4 b = *(const float4*)&row[tid * 8 + 4];
    float v[8] = {a.x, a.y, a.z, a.w, b.x, b.y, b.z, b.w};

    float m = v[0];
#pragma unroll
    for (int j = 1; j < 8; j++) m = fmaxf(m, v[j]);
    for (int o = 32; o; o >>= 1) m = fmaxf(m, __shfl_xor(m, o));
    __shared__ float redm[4], reds[4];
    if ((tid & 63) == 0) redm[tid >> 6] = m;
    __syncthreads();
    m = fmaxf(fmaxf(redm[0], redm[1]), fmaxf(redm[2], redm[3]));

    float e[8], s = 0.f;
#pragma unroll
    for (int j = 0; j < 8; j++) { e[j] = __expf(v[j] - m); s += e[j]; }
    for (int o = 32; o; o >>= 1) s += __shfl_xor(s, o);
    if ((tid & 63) == 0) reds[tid >> 6] = s;
    __syncthreads();
    s = reds[0] + reds[1] + reds[2] + reds[3];
    const float inv = 1.f / s;

    u16* ph = (u16*)row;          // all reads of this row completed (barriers)
    ushort4 h0, h1;
    h0.x = f2bf(e[0] * inv); h0.y = f2bf(e[1] * inv);
    h0.z = f2bf(e[2] * inv); h0.w = f2bf(e[3] * inv);
    h1.x = f2bf(e[4] * inv); h1.y = f2bf(e[5] * inv);
    h1.z = f2bf(e[6] * inv); h1.w = f2bf(e[7] * inv);
    *(ushort4*)&ph[tid * 8]     = h0;
    *(ushort4*)&ph[tid * 8 + 4] = h1;
}

// ---------------------------------------------------------------------------
// colsum[b][k] = sum_l P2[b][l][k]   (P bf16 rows at u16-stride 4096)
// grid (4, 8), 256 thr
// ---------------------------------------------------------------------------
__global__ __launch_bounds__(256) void colsum_P(
    const u16* __restrict__ P, float* __restrict__ csum)
{
    const int b = blockIdx.x;
    const int k = blockIdx.y * 256 + threadIdx.x;
    const u16* base = P + (size_t)b * 2048 * 4096 + k;
    float s = 0.f;
#pragma unroll 8
    for (int l = 0; l < 2048; l++) s += bf2f(base[(size_t)l * 4096]);
    csum[b * 2048 + k] = s;
}

// ---------------------------------------------------------------------------
// partial[b*4+ch] = sum_{d in chunk} WO[d] * (colsum[b] . Vt[b][d][:])
// grid (4, 4), 256 thr
// ---------------------------------------------------------------------------
__global__ __launch_bounds__(256) void matvec_head(
    const float* __restrict__ csum, const u16* __restrict__ Vtb,
    const float* __restrict__ wO, float* __restrict__ partial)
{
    const int b = blockIdx.x, chnk = blockIdx.y;
    __shared__ float c[2048];
    for (int i = threadIdx.x; i < 2048; i += 256) c[i] = csum[b * 2048 + i];
    __syncthreads();
    const int d = chnk * 256 + threadIdx.x;
    const u16* vr = Vtb + (size_t)b * (2048 * 1024) + (size_t)d * 2048;
    float acc = 0.f;
    for (int l0 = 0; l0 < 2048; l0 += 8) {
        const bf16x8 v = *(const bf16x8*)&vr[l0];
#pragma unroll
        for (int j = 0; j < 8; j++) acc += c[l0 + j] * bf2f((u16)v[j]);
    }
    float val = acc * wO[d];
    for (int o = 32; o; o >>= 1) val += __shfl_xor(val, o);
    __shared__ float red[4];
    if ((threadIdx.x & 63) == 0) red[threadIdx.x >> 6] = val;
    __syncthreads();
    if (threadIdx.x == 0) partial[b * 4 + chnk] = red[0] + red[1] + red[2] + red[3];
}

__global__ void head_final(const float* __restrict__ partial,
                           const float* __restrict__ bO, float* __restrict__ out)
{
    const int b = threadIdx.x;                  // 0..3
    if (b >= 4) return;
    const float s = partial[b * 4] + partial[b * 4 + 1]
                  + partial[b * 4 + 2] + partial[b * 4 + 3];
    const float logit = s * (1.f / 2048.f) + bO[0];
    out[b] = 1.f / (1.f + __expf(-logit));
}

// ---------------------------------------------------------------------------
extern "C" void kernel_launch(void* const* d_in, const int* in_sizes, int n_in,
                              void* d_out, int out_size, void* d_ws, size_t ws_size,
                              hipStream_t stream)
{
    const float* X   = (const float*)d_in[0];
    const float* Wq1 = (const float*)d_in[1];
    const float* Wk1 = (const float*)d_in[2];
    const float* Wv1 = (const float*)d_in[3];
    const float* Wq2 = (const float*)d_in[4];
    const float* Wk2 = (const float*)d_in[5];
    const float* Wv2 = (const float*)d_in[6];
    const float* WO  = (const float*)d_in[7];
    const float* bO  = (const float*)d_in[8];
    float* out = (float*)d_out;

    uint8_t* ws = (uint8_t*)d_ws;
    const size_t MB = 1ull << 20;
    u16* Xb   = (u16*)(ws + 0);          // X bf16; later H1 bf16
    u16* Qb   = (u16*)(ws + 32 * MB);    // Q bf16
    u16* Kb   = (u16*)(ws + 64 * MB);    // K bf16
    float* partial = (float*)(ws + 80 * MB);
    float* csum    = (float*)(ws + 81 * MB);   // 4 x 2048 fp32
    u16* Vtb  = (u16*)(ws + 96 * MB);    // V^T bf16 per-batch
    u16* Wcat = (u16*)(ws + 128 * MB);   // 2 x (3072 x 1024) bf16
    float* S  = (float*)(ws + 152 * MB); // 64 MB scores / P

    // ---- prep: cast X to bf16, batched weight transpose into Wcat
    cast_bf16<<<8192, 256, 0, stream>>>(X, Xb);   // 8M elems
    transpose_cat<<<dim3(16, 16, 6), 256, 0, stream>>>(
        Wq1, Wk1, Wv1, Wq2, Wk2, Wv2, Wcat);

    const long long LD2 = 2048LL * 1024;   // 2M: Q/K/V batch stride
    const long long SST = 2048LL * 2048;   // 4M: S batch stride (floats)
    const long long PST = 2048LL * 4096;   // 8M: P batch stride (u16)

    for (int blk = 0; blk < 2; blk++) {
        // fused Q|K|V projection: grid (3072/128=24, 8192/128=64) = 1536
        gemmk<4><<<dim3(24, 64, 1), 256, 0, stream>>>(
            Xb, 0, Wcat + (size_t)blk * (3072 * 1024), 0,
            Qb, Kb, Vtb, 0,
            8192, 3072, 1024, 1024, 1024, 0, 1.f);
        // S = Q.K^T / sqrt(D): grid (16, 16, 4) = 1024 blocks
        gemmk<1><<<dim3(16, 16, 4), 256, 0, stream>>>(
            Qb, LD2, Kb, LD2, S, nullptr, nullptr, SST,
            2048, 2048, 1024, 1024, 1024, 2048, 0.03125f);
        // softmax rows, in-place -> P bf16
        softmax_rows<<<8192, 256, 0, stream>>>(S);
        if (blk == 0) {
            // PV-1: H1 bf16 -> Xb region.  grid (8, 16, 4) = 512 blocks
            gemmk<3><<<dim3(8, 16, 4), 256, 0, stream>>>(
                (u16*)S, PST, Vtb, LD2, Xb, nullptr, nullptr, LD2,
                2048, 1024, 2048, 4096, 2048, 1024, 1.f);
        }
    }

    // head: pooled = (1/L)(1^T P2) V2;  logit = pooled . WO + bO
    colsum_P<<<dim3(4, 8), 256, 0, stream>>>((const u16*)S, csum);
    matvec_head<<<dim3(4, 4), 256, 0, stream>>>(csum, Vtb, WO, partial);
    head_final<<<1, 64, 0, stream>>>(partial, bO, out);
}

// Round 12
// 340.383 us; speedup vs baseline: 1.4469x; 1.4469x over previous
//
#include <hip/hip_runtime.h>
#include <hip/hip_bf16.h>
#include <cstdint>

// ---------------------------------------------------------------------------
// TransformerClassifier: 2x single-head attention (N=4, L=2048, D=1024) +
// mean-pool + linear + sigmoid.
//
// v10 = v9 with the head path fixed (R11 post-mortem: colsum_P 32-block /
// matvec_head 16-block launch starvation, 102+~60us) and one more algebraic
// elimination:
//   pooled.WO = (1/L)(1^T P2) V2 WO = (1/L) csum . (H1 (W_V2 WO))
//   -> layer-2 V projection GEMM deleted entirely; instead
//      wv = W_V2.WO (fp32, tiny), u = H1.wv (matvec, 512 blocks),
//      logit = (1/L) csum.u  (+ accuracy: V2 never rounded to bf16 here).
//   colsum(P2) now a two-stage deterministic reduction (512 blocks).
//   Layer-2 fused projection shrinks to Q|K only (N=2048).
//
// GEMM (unchanged, proven R9/R10): 128x128 tile, BK=32, 256 thr (4 waves,
// 64x64), double-buffered LDS (16KB/buf), ONE __syncthreads per K-tile,
// global_load_lds with pre-swizzled global sources; A/B rows = 4x16B slots,
// slot = chunk ^ ((row>>1)&3)  (0 bank conflicts).
//
// ws layout (216 MB):
//   [  0MB) Xb    : X bf16; overwritten by H1 bf16        (16 MB)
//   [ 32MB) Qb    : Q bf16                                 (16 MB)
//   [ 64MB) Kb    : K bf16                                 (16 MB)
//   [ 80MB) head scratch: csum_part/csum/wv/u/partial      (~1 MB)
//   [ 96MB) Vtb   : V^T bf16 (per-batch [d][l], layer 1)   (16 MB)
//   [128MB) Wcat  : layer1 3072x1024 + layer2 2048x1024 W^T bf16 (10 MB)
//   [152MB) S/P   : scores fp32 -> P bf16 in place         (64 MB)
// ---------------------------------------------------------------------------

#define DEVFN __device__ __forceinline__

typedef __attribute__((ext_vector_type(8))) short bf16x8;
typedef __attribute__((ext_vector_type(4))) float f32x4;
typedef unsigned short u16;

DEVFN u16 f2bf(float f) {               // round-to-nearest-even bf16 (finite)
    uint32_t x = __float_as_uint(f);
    x += 0x7fffu + ((x >> 16) & 1u);
    return (u16)(x >> 16);
}
DEVFN float bf2f(u16 u) { return __uint_as_float(((uint32_t)u) << 16); }

DEVFN void gload_lds16(const void* g, void* l) {
    __builtin_amdgcn_global_load_lds(
        (const __attribute__((address_space(1))) void*)g,
        (__attribute__((address_space(3))) void*)l, 16, 0, 0);
}

#define MFMA16 __builtin_amdgcn_mfma_f32_16x16x32_bf16

// ---------------------------------------------------------------------------
// bf16 GEMM:  C = scale * (A . B^T)
//   A : M x K row-major bf16 (lda);  B : N x K row-major bf16 (ldb)
// Tile 128x128, BK=32.  grid (N/128, M/128, Z), total blocks % 8 == 0.
// EPI: 1 = fp32 row-major (out0)
//      3 = bf16 row-major (out0)
//      4 = fused-QKV routing: seg 0 -> out0 (Q), seg 1 -> out1 (K),
//          seg 2 -> out2 (V^T per-batch)   [seg = n0>>10]
// ---------------------------------------------------------------------------
template<int EPI>
__global__ __launch_bounds__(256, 4) void gemmk(
    const u16* __restrict__ A, long long aStride,
    const u16* __restrict__ B, long long bStride,
    void* __restrict__ out0, void* __restrict__ out1, void* __restrict__ out2,
    long long cStride,
    int M, int N, int K, int lda, int ldb, int ldc, float scale)
{
    constexpr int ASEC  = 128 * 32;          // u16 per buffer, A section
    constexpr int BUFSZ = ASEC + 128 * 32;   // + B section
    constexpr int NU    = 4;                 // stage units (A:2, B:2)

    __shared__ __align__(16) u16 L[2 * BUFSZ];
    const int tid  = threadIdx.x;
    const int wave = tid >> 6, lane = tid & 63;

    // bijective XCD-aware block swizzle (all launches have nwg % 8 == 0)
    const int gx = gridDim.x, gy = gridDim.y;
    const int nwg = gx * gy * gridDim.z;
    int flat = (blockIdx.z * gy + blockIdx.y) * gx + blockIdx.x;
    flat = (flat & 7) * (nwg >> 3) + (flat >> 3);
    const int bx = flat % gx, by = (flat / gx) % gy, bz = flat / (gx * gy);

    const u16* pA = A + (size_t)bz * aStride;
    const u16* pB = B + (size_t)bz * bStride;
    const int m0 = by * 128, n0 = bx * 128;

    // ---- staging units: each = 2048 u16 (256 thr x 16B), linear LDS dest;
    // 4 slots/row, stored chunk = slot ^ ((row>>1)&3)  (pre-swizzled source)
    const u16* src[NU];
    int dst[NU];
#pragma unroll
    for (int q = 0; q < 2; q++) {
        const int s = q * 256 + tid, row = s >> 2, c = (s & 3) ^ ((row >> 1) & 3);
        src[q]     = pA + (size_t)(m0 + row) * lda + c * 8;
        dst[q]     = q * 2048 + wave * 512;
        src[2 + q] = pB + (size_t)(n0 + row) * ldb + c * 8;
        dst[2 + q] = ASEC + q * 2048 + wave * 512;
    }

    // ---- fragment geometry (16x16 frags; wave = 64x64 quadrant)
    const int fr = lane & 15, ch = lane >> 4;
    const int wr = (wave >> 1) * 64, wc = (wave & 1) * 64;

    const int NT = K >> 5;

    // ---- prologue: stage tile 0 into buffer 0
#pragma unroll
    for (int u = 0; u < NU; u++) { gload_lds16(src[u], &L[dst[u]]); src[u] += 32; }
    __syncthreads();

    f32x4 acc[4][4] = {};
    int cur = 0;

    for (int kt = 0; kt < NT; ++kt) {
        const int cOff = cur * BUFSZ;
        const int sOff = BUFSZ - cOff;
        if (kt + 1 < NT) {
#pragma unroll
            for (int u = 0; u < NU; u++) { gload_lds16(src[u], &L[sOff + dst[u]]); src[u] += 32; }
        }

        bf16x8 ah[4], bh[4];
#pragma unroll
        for (int i = 0; i < 4; i++) {
            const int r = wr + i * 16 + fr;
            ah[i] = *(const bf16x8*)&L[cOff + r * 32 + ((ch ^ ((r >> 1) & 3)) << 3)];
        }
#pragma unroll
        for (int j = 0; j < 4; j++) {
            const int r = wc + j * 16 + fr;
            bh[j] = *(const bf16x8*)&L[cOff + ASEC + r * 32 + ((ch ^ ((r >> 1) & 3)) << 3)];
        }

#pragma unroll
        for (int i = 0; i < 4; i++)
#pragma unroll
            for (int j = 0; j < 4; j++)
                acc[i][j] = MFMA16(ah[i], bh[j], acc[i][j], 0, 0, 0);

        __syncthreads();     // drains vmcnt (staging) + lgkm; swap buffers
        cur ^= 1;
    }

    // ---- epilogue: C/D layout col = lane&15, row = (lane>>4)*4 + r
    const int seg = n0 >> 10;               // uniform per block (EPI 4)
#pragma unroll
    for (int i = 0; i < 4; i++)
#pragma unroll
        for (int j = 0; j < 4; j++)
#pragma unroll
            for (int r = 0; r < 4; r++) {
                const int row = m0 + wr + i * 16 + (lane >> 4) * 4 + r;
                const int col = n0 + wc + j * 16 + (lane & 15);
                const float v = acc[i][j][r] * scale;
                if constexpr (EPI == 1) {
                    ((float*)out0)[(size_t)bz * cStride + (size_t)row * ldc + col] = v;
                } else if constexpr (EPI == 3) {
                    ((u16*)out0)[(size_t)bz * cStride + (size_t)row * ldc + col] = f2bf(v);
                } else {  // EPI == 4: fused QKV routing
                    const int c = col & 1023;
                    if (seg == 0) {
                        ((u16*)out0)[(size_t)row * 1024 + c] = f2bf(v);
                    } else if (seg == 1) {
                        ((u16*)out1)[(size_t)row * 1024 + c] = f2bf(v);
                    } else {  // V^T per-batch: [b][d][l]
                        const int b = row >> 11, ll = row & 2047;
                        ((u16*)out2)[(size_t)b * (2048 * 1024) + (size_t)c * 2048 + ll] = f2bf(v);
                    }
                }
            }
}

// ---------------------------------------------------------------------------
__global__ __launch_bounds__(256) void cast_bf16(
    const float* __restrict__ x, u16* __restrict__ o)
{
    const size_t i = ((size_t)blockIdx.x * 256 + threadIdx.x) * 4;
    const float4 v = *(const float4*)&x[i];
    ushort4 h;
    h.x = f2bf(v.x); h.y = f2bf(v.y); h.z = f2bf(v.z); h.w = f2bf(v.w);
    *(ushort4*)&o[i] = h;
}

// ---------------------------------------------------------------------------
// Batched W -> W^T bf16 into Wcat:
//   layer1 rows [0,3072): W_Q1^T | W_K1^T | W_V1^T
//   layer2 rows [3072,5120): W_Q2^T | W_K2^T      (W_V2 not transposed)
// grid (16, 16, 5)
// ---------------------------------------------------------------------------
__global__ __launch_bounds__(256) void transpose_cat(
    const float* __restrict__ W0, const float* __restrict__ W1,
    const float* __restrict__ W2, const float* __restrict__ W3,
    const float* __restrict__ W4, u16* __restrict__ Wcat)
{
    const int w = blockIdx.z;
    const float* W = (w == 0) ? W0 : (w == 1) ? W1 : (w == 2) ? W2
                   : (w == 3) ? W3 : W4;
    u16* dstb = Wcat + (size_t)w * (1024 * 1024);
    __shared__ float t[64][65];
    const int tid = threadIdx.x;
    const int r0 = blockIdx.y * 64, c0 = blockIdx.x * 64;
#pragma unroll
    for (int it = 0; it < 16; it++) {
        const int idx = it * 256 + tid, rr = idx >> 6, cc = idx & 63;
        t[rr][cc] = W[(size_t)(r0 + rr) * 1024 + (c0 + cc)];
    }
    __syncthreads();
#pragma unroll
    for (int it = 0; it < 16; it++) {
        const int idx = it * 256 + tid, nn = idx >> 6, kk = idx & 63;
        dstb[(size_t)(c0 + nn) * 1024 + (r0 + kk)] = f2bf(t[kk][nn]);
    }
}

// ---------------------------------------------------------------------------
// Row softmax over 2048 fp32 scores, written IN PLACE as P bf16 (row head)
// ---------------------------------------------------------------------------
__global__ __launch_bounds__(256) void softmax_rows(float* __restrict__ S)
{
    const int r   = blockIdx.x;                 // 0..8191 (batch*2048 + l)
    float* row    = S + (size_t)r * 2048;
    const int tid = threadIdx.x;

    const float4 a = *(const float4*)&row[tid * 8];
    const float4 b = *(const float4*)&row[tid * 8 + 4];
    float v[8] = {a.x, a.y, a.z, a.w, b.x, b.y, b.z, b.w};

    float m = v[0];
#pragma unroll
    for (int j = 1; j < 8; j++) m = fmaxf(m, v[j]);
    for (int o = 32; o; o >>= 1) m = fmaxf(m, __shfl_xor(m, o));
    __shared__ float redm[4], reds[4];
    if ((tid & 63) == 0) redm[tid >> 6] = m;
    __syncthreads();
    m = fmaxf(fmaxf(redm[0], redm[1]), fmaxf(redm[2], redm[3]));

    float e[8], s = 0.f;
#pragma unroll
    for (int j = 0; j < 8; j++) { e[j] = __expf(v[j] - m); s += e[j]; }
    for (int o = 32; o; o >>= 1) s += __shfl_xor(s, o);
    if ((tid & 63) == 0) reds[tid >> 6] = s;
    __syncthreads();
    s = reds[0] + reds[1] + reds[2] + reds[3];
    const float inv = 1.f / s;

    u16* ph = (u16*)row;          // all reads of this row completed (barriers)
    ushort4 h0, h1;
    h0.x = f2bf(e[0] * inv); h0.y = f2bf(e[1] * inv);
    h0.z = f2bf(e[2] * inv); h0.w = f2bf(e[3] * inv);
    h1.x = f2bf(e[4] * inv); h1.y = f2bf(e[5] * inv);
    h1.z = f2bf(e[6] * inv); h1.w = f2bf(e[7] * inv);
    *(ushort4*)&ph[tid * 8]     = h0;
    *(ushort4*)&ph[tid * 8 + 4] = h1;
}

// ---------------------------------------------------------------------------
// Stage 1: part[b][lc][k] = sum over 128 rows of P2[b][l][k]
// grid (4, 8, 16), 256 thr  (512 blocks; coalesced 512B row segments)
// ---------------------------------------------------------------------------
__global__ __launch_bounds__(256) void colsum_part(
    const u16* __restrict__ P, float* __restrict__ part)
{
    const int b = blockIdx.x, kc = blockIdx.y, lc = blockIdx.z;
    const int k = kc * 256 + threadIdx.x;
    const u16* base = P + (size_t)b * 2048 * 4096 + (size_t)lc * 128 * 4096 + k;
    float s = 0.f;
#pragma unroll 8
    for (int l = 0; l < 128; l++) s += bf2f(base[(size_t)l * 4096]);
    part[((size_t)b * 16 + lc) * 2048 + k] = s;
}

// Stage 2: csum[b][k] = sum_lc part[b][lc][k].  grid (4, 8), 256 thr
__global__ __launch_bounds__(256) void colsum_reduce(
    const float* __restrict__ part, float* __restrict__ csum)
{
    const int b = blockIdx.x, k = blockIdx.y * 256 + threadIdx.x;
    float s = 0.f;
#pragma unroll
    for (int lc = 0; lc < 16; lc++)
        s += part[((size_t)b * 16 + lc) * 2048 + k];
    csum[b * 2048 + k] = s;
}

// ---------------------------------------------------------------------------
// wv[d] = W_V2[d][:] . wO    (fp32 x fp32, rows of W_V2)
// grid (64), 256 thr = 16 rows x 16 lanes; lane reads float4 coalesced
// ---------------------------------------------------------------------------
__global__ __launch_bounds__(256) void wv_dot(
    const float* __restrict__ Wv2, const float* __restrict__ wO,
    float* __restrict__ wv)
{
    const int d = blockIdx.x * 16 + (threadIdx.x >> 4);
    const int lx = threadIdx.x & 15;
    const float* row = Wv2 + (size_t)d * 1024;
    float s = 0.f;
#pragma unroll
    for (int it = 0; it < 16; it++) {
        const int j = it * 64 + lx * 4;
        const float4 a = *(const float4*)&row[j];
        const float4 w = *(const float4*)&wO[j];
        s += a.x * w.x + a.y * w.y + a.z * w.z + a.w * w.w;
    }
#pragma unroll
    for (int o = 8; o; o >>= 1) s += __shfl_xor(s, o, 16);
    if (lx == 0) wv[d] = s;
}

// ---------------------------------------------------------------------------
// u[r] = H1[r][:] . wv     (H1 bf16 8192x1024)
// grid (512), 256 thr = 16 rows x 16 lanes; lane reads bf16x8 coalesced
// ---------------------------------------------------------------------------
__global__ __launch_bounds__(256) void u_dot(
    const u16* __restrict__ H1, const float* __restrict__ wv,
    float* __restrict__ u)
{
    const int r = blockIdx.x * 16 + (threadIdx.x >> 4);
    const int lx = threadIdx.x & 15;
    const u16* row = H1 + (size_t)r * 1024;
    float s = 0.f;
#pragma unroll
    for (int it = 0; it < 8; it++) {
        const int d = it * 128 + lx * 8;
        const bf16x8 h = *(const bf16x8*)&row[d];
#pragma unroll
        for (int j = 0; j < 8; j++) s += bf2f((u16)h[j]) * wv[d + j];
    }
#pragma unroll
    for (int o = 8; o; o >>= 1) s += __shfl_xor(s, o, 16);
    if (lx == 0) u[r] = s;
}

// ---------------------------------------------------------------------------
// out[b] = sigmoid( (1/L) csum[b].u[b] + bO );  1 block, 256 thr (4b x 64)
// ---------------------------------------------------------------------------
__global__ void head_final(const float* __restrict__ csum,
                           const float* __restrict__ u,
                           const float* __restrict__ bO, float* __restrict__ out)
{
    const int b = threadIdx.x >> 6, lane = threadIdx.x & 63;
    float s = 0.f;
    for (int k = lane; k < 2048; k += 64)
        s += csum[b * 2048 + k] * u[b * 2048 + k];
    for (int o = 32; o; o >>= 1) s += __shfl_xor(s, o);
    if (lane == 0) {
        const float logit = s * (1.f / 2048.f) + bO[0];
        out[b] = 1.f / (1.f + __expf(-logit));
    }
}

// ---------------------------------------------------------------------------
extern "C" void kernel_launch(void* const* d_in, const int* in_sizes, int n_in,
                              void* d_out, int out_size, void* d_ws, size_t ws_size,
                              hipStream_t stream)
{
    const float* X   = (const float*)d_in[0];
    const float* Wq1 = (const float*)d_in[1];
    const float* Wk1 = (const float*)d_in[2];
    const float* Wv1 = (const float*)d_in[3];
    const float* Wq2 = (const float*)d_in[4];
    const float* Wk2 = (const float*)d_in[5];
    const float* Wv2 = (const float*)d_in[6];
    const float* WO  = (const float*)d_in[7];
    const float* bO  = (const float*)d_in[8];
    float* out = (float*)d_out;

    uint8_t* ws = (uint8_t*)d_ws;
    const size_t MB = 1ull << 20;
    u16* Xb   = (u16*)(ws + 0);          // X bf16; later H1 bf16
    u16* Qb   = (u16*)(ws + 32 * MB);    // Q bf16
    u16* Kb   = (u16*)(ws + 64 * MB);    // K bf16
    float* part = (float*)(ws + 80 * MB);        // 4x16x2048 fp32 (512 KB)
    float* csum = (float*)(ws + 81 * MB);        // 4x2048
    float* wv   = (float*)(ws + 82 * MB);        // 1024
    float* ud   = (float*)(ws + 83 * MB);        // 8192
    u16* Vtb  = (u16*)(ws + 96 * MB);    // V^T bf16 per-batch (layer 1)
    u16* Wcat = (u16*)(ws + 128 * MB);   // 5 x (1024x1024) bf16
    float* S  = (float*)(ws + 152 * MB); // 64 MB scores / P

    // ---- prep
    cast_bf16<<<8192, 256, 0, stream>>>(X, Xb);   // 8M elems
    transpose_cat<<<dim3(16, 16, 5), 256, 0, stream>>>(
        Wq1, Wk1, Wv1, Wq2, Wk2, Wcat);
    wv_dot<<<64, 256, 0, stream>>>(Wv2, WO, wv);

    const long long LD2 = 2048LL * 1024;   // 2M: Q/K/V batch stride
    const long long SST = 2048LL * 2048;   // 4M: S batch stride (floats)
    const long long PST = 2048LL * 4096;   // 8M: P batch stride (u16)

    // ======== layer 1 ========
    gemmk<4><<<dim3(24, 64, 1), 256, 0, stream>>>(     // Q|K|V fused
        Xb, 0, Wcat, 0, Qb, Kb, Vtb, 0,
        8192, 3072, 1024, 1024, 1024, 0, 1.f);
    gemmk<1><<<dim3(16, 16, 4), 256, 0, stream>>>(     // S = Q.K^T/32
        Qb, LD2, Kb, LD2, S, nullptr, nullptr, SST,
        2048, 2048, 1024, 1024, 1024, 2048, 0.03125f);
    softmax_rows<<<8192, 256, 0, stream>>>(S);
    gemmk<3><<<dim3(8, 16, 4), 256, 0, stream>>>(      // H1 = P.V -> Xb
        (u16*)S, PST, Vtb, LD2, Xb, nullptr, nullptr, LD2,
        2048, 1024, 2048, 4096, 2048, 1024, 1.f);

    // ======== layer 2 (no V projection needed) ========
    gemmk<4><<<dim3(16, 64, 1), 256, 0, stream>>>(     // Q|K fused
        Xb, 0, Wcat + 3ull * (1024 * 1024), 0, Qb, Kb, nullptr, 0,
        8192, 2048, 1024, 1024, 1024, 0, 1.f);
    gemmk<1><<<dim3(16, 16, 4), 256, 0, stream>>>(
        Qb, LD2, Kb, LD2, S, nullptr, nullptr, SST,
        2048, 2048, 1024, 1024, 1024, 2048, 0.03125f);
    softmax_rows<<<8192, 256, 0, stream>>>(S);

    // ======== head: logit = (1/L) colsum(P2) . (H1.(W_V2.WO)) + bO ========
    colsum_part<<<dim3(4, 8, 16), 256, 0, stream>>>((const u16*)S, part);
    colsum_reduce<<<dim3(4, 8), 256, 0, stream>>>(part, csum);
    u_dot<<<512, 256, 0, stream>>>(Xb, wv, ud);
    head_final<<<1, 256, 0, stream>>>(csum, ud, bO, out);
}

// Round 13
// 323.792 us; speedup vs baseline: 1.5211x; 1.0512x over previous
//
#include <hip/hip_runtime.h>
#include <hip/hip_bf16.h>
#include <cstdint>

// ---------------------------------------------------------------------------
// TransformerClassifier: 2x single-head attention (N=4, L=2048, D=1024) +
// mean-pool + linear + sigmoid.
//
// v11 = v10 with two fixes from the R12 profile:
//   * QKV fusion REVERTED (R12: fused proj = 95us, FETCH 78MB -- each XCD
//     streamed all 6MB of Wcat through its 4MB L2).  Separate launches keep
//     B (2MB) L2-resident; B pointers index into the same Wcat buffer.
//   * Layer-2 softmax + colsum stage-1 FUSED (P2 is consumed only by the
//     column-sum): 16 rows/block, per-thread column partials in registers.
//     Removes the 32MB P2 write + 32MB colsum read (-> 4MB partials).
//
// GEMM (unchanged, proven R9/R10): 128x128 tile, BK=32, 256 thr (4 waves,
// 64x64), double-buffered LDS (16KB/buf), ONE __syncthreads per K-tile,
// global_load_lds with pre-swizzled global sources; A/B rows = 4x16B slots,
// slot = chunk ^ ((row>>1)&3)  (0 bank conflicts).
//
// Head algebra (exact):  pooled.WO = (1/L)(1^T P2) V2 WO
//                                 = (1/L) colsum(P2) . (H1 . (W_V2.WO))
//
// ws layout (216 MB):
//   [  0MB) Xb    : X bf16; overwritten by H1 bf16        (16 MB)
//   [ 32MB) Qb    : Q bf16                                 (16 MB)
//   [ 64MB) Kb    : K bf16                                 (16 MB)
//   [ 80MB) head scratch: part/csum/wv/u                   (~6 MB)
//   [ 96MB) Vtb   : V^T bf16 (per-batch [d][l], layer 1)   (16 MB)
//   [128MB) Wcat  : 5 x (1024x1024) W^T bf16               (10 MB)
//   [152MB) S/P   : scores fp32 (P1 bf16 in place)         (64 MB)
// ---------------------------------------------------------------------------

#define DEVFN __device__ __forceinline__

typedef __attribute__((ext_vector_type(8))) short bf16x8;
typedef __attribute__((ext_vector_type(4))) float f32x4;
typedef unsigned short u16;

DEVFN u16 f2bf(float f) {               // round-to-nearest-even bf16 (finite)
    uint32_t x = __float_as_uint(f);
    x += 0x7fffu + ((x >> 16) & 1u);
    return (u16)(x >> 16);
}
DEVFN float bf2f(u16 u) { return __uint_as_float(((uint32_t)u) << 16); }

DEVFN void gload_lds16(const void* g, void* l) {
    __builtin_amdgcn_global_load_lds(
        (const __attribute__((address_space(1))) void*)g,
        (__attribute__((address_space(3))) void*)l, 16, 0, 0);
}

#define MFMA16 __builtin_amdgcn_mfma_f32_16x16x32_bf16

// ---------------------------------------------------------------------------
// bf16 GEMM:  C = scale * (A . B^T)
//   A : M x K row-major bf16 (lda);  B : N x K row-major bf16 (ldb)
// Tile 128x128, BK=32.  grid (N/128, M/128, Z), total blocks % 8 == 0.
// EPI: 1 = fp32 row-major;  2 = V^T bf16 per-batch;  3 = bf16 row-major
// ---------------------------------------------------------------------------
template<int EPI>
__global__ __launch_bounds__(256, 4) void gemmk(
    const u16* __restrict__ A, long long aStride,
    const u16* __restrict__ B, long long bStride,
    void* __restrict__ out0, long long cStride,
    int M, int N, int K, int lda, int ldb, int ldc, float scale)
{
    constexpr int ASEC  = 128 * 32;          // u16 per buffer, A section
    constexpr int BUFSZ = ASEC + 128 * 32;   // + B section
    constexpr int NU    = 4;                 // stage units (A:2, B:2)

    __shared__ __align__(16) u16 L[2 * BUFSZ];
    const int tid  = threadIdx.x;
    const int wave = tid >> 6, lane = tid & 63;

    // bijective XCD-aware block swizzle (all launches have nwg % 8 == 0)
    const int gx = gridDim.x, gy = gridDim.y;
    const int nwg = gx * gy * gridDim.z;
    int flat = (blockIdx.z * gy + blockIdx.y) * gx + blockIdx.x;
    flat = (flat & 7) * (nwg >> 3) + (flat >> 3);
    const int bx = flat % gx, by = (flat / gx) % gy, bz = flat / (gx * gy);

    const u16* pA = A + (size_t)bz * aStride;
    const u16* pB = B + (size_t)bz * bStride;
    const int m0 = by * 128, n0 = bx * 128;

    // ---- staging units: each = 2048 u16 (256 thr x 16B), linear LDS dest;
    // 4 slots/row, stored chunk = slot ^ ((row>>1)&3)  (pre-swizzled source)
    const u16* src[NU];
    int dst[NU];
#pragma unroll
    for (int q = 0; q < 2; q++) {
        const int s = q * 256 + tid, row = s >> 2, c = (s & 3) ^ ((row >> 1) & 3);
        src[q]     = pA + (size_t)(m0 + row) * lda + c * 8;
        dst[q]     = q * 2048 + wave * 512;
        src[2 + q] = pB + (size_t)(n0 + row) * ldb + c * 8;
        dst[2 + q] = ASEC + q * 2048 + wave * 512;
    }

    // ---- fragment geometry (16x16 frags; wave = 64x64 quadrant)
    const int fr = lane & 15, ch = lane >> 4;
    const int wr = (wave >> 1) * 64, wc = (wave & 1) * 64;

    const int NT = K >> 5;

    // ---- prologue: stage tile 0 into buffer 0
#pragma unroll
    for (int u = 0; u < NU; u++) { gload_lds16(src[u], &L[dst[u]]); src[u] += 32; }
    __syncthreads();

    f32x4 acc[4][4] = {};
    int cur = 0;

    for (int kt = 0; kt < NT; ++kt) {
        const int cOff = cur * BUFSZ;
        const int sOff = BUFSZ - cOff;
        if (kt + 1 < NT) {
#pragma unroll
            for (int u = 0; u < NU; u++) { gload_lds16(src[u], &L[sOff + dst[u]]); src[u] += 32; }
        }

        bf16x8 ah[4], bh[4];
#pragma unroll
        for (int i = 0; i < 4; i++) {
            const int r = wr + i * 16 + fr;
            ah[i] = *(const bf16x8*)&L[cOff + r * 32 + ((ch ^ ((r >> 1) & 3)) << 3)];
        }
#pragma unroll
        for (int j = 0; j < 4; j++) {
            const int r = wc + j * 16 + fr;
            bh[j] = *(const bf16x8*)&L[cOff + ASEC + r * 32 + ((ch ^ ((r >> 1) & 3)) << 3)];
        }

#pragma unroll
        for (int i = 0; i < 4; i++)
#pragma unroll
            for (int j = 0; j < 4; j++)
                acc[i][j] = MFMA16(ah[i], bh[j], acc[i][j], 0, 0, 0);

        __syncthreads();     // drains vmcnt (staging) + lgkm; swap buffers
        cur ^= 1;
    }

    // ---- epilogue: C/D layout col = lane&15, row = (lane>>4)*4 + r
#pragma unroll
    for (int i = 0; i < 4; i++)
#pragma unroll
        for (int j = 0; j < 4; j++)
#pragma unroll
            for (int r = 0; r < 4; r++) {
                const int row = m0 + wr + i * 16 + (lane >> 4) * 4 + r;
                const int col = n0 + wc + j * 16 + (lane & 15);
                const float v = acc[i][j][r] * scale;
                if constexpr (EPI == 1) {
                    ((float*)out0)[(size_t)bz * cStride + (size_t)row * ldc + col] = v;
                } else if constexpr (EPI == 2) {  // V^T bf16, per-batch
                    const int b = row >> 11, ll = row & 2047;
                    ((u16*)out0)[(size_t)b * (2048 * 1024) + (size_t)col * 2048 + ll] = f2bf(v);
                } else {                          // EPI == 3: bf16 row-major
                    ((u16*)out0)[(size_t)bz * cStride + (size_t)row * ldc + col] = f2bf(v);
                }
            }
}

// ---------------------------------------------------------------------------
__global__ __launch_bounds__(256) void cast_bf16(
    const float* __restrict__ x, u16* __restrict__ o)
{
    const size_t i = ((size_t)blockIdx.x * 256 + threadIdx.x) * 4;
    const float4 v = *(const float4*)&x[i];
    ushort4 h;
    h.x = f2bf(v.x); h.y = f2bf(v.y); h.z = f2bf(v.z); h.w = f2bf(v.w);
    *(ushort4*)&o[i] = h;
}

// ---------------------------------------------------------------------------
// Batched W -> W^T bf16: Wcat slots {Wq1,Wk1,Wv1,Wq2,Wk2}.  grid (16,16,5)
// ---------------------------------------------------------------------------
__global__ __launch_bounds__(256) void transpose_cat(
    const float* __restrict__ W0, const float* __restrict__ W1,
    const float* __restrict__ W2, const float* __restrict__ W3,
    const float* __restrict__ W4, u16* __restrict__ Wcat)
{
    const int w = blockIdx.z;
    const float* W = (w == 0) ? W0 : (w == 1) ? W1 : (w == 2) ? W2
                   : (w == 3) ? W3 : W4;
    u16* dstb = Wcat + (size_t)w * (1024 * 1024);
    __shared__ float t[64][65];
    const int tid = threadIdx.x;
    const int r0 = blockIdx.y * 64, c0 = blockIdx.x * 64;
#pragma unroll
    for (int it = 0; it < 16; it++) {
        const int idx = it * 256 + tid, rr = idx >> 6, cc = idx & 63;
        t[rr][cc] = W[(size_t)(r0 + rr) * 1024 + (c0 + cc)];
    }
    __syncthreads();
#pragma unroll
    for (int it = 0; it < 16; it++) {
        const int idx = it * 256 + tid, nn = idx >> 6, kk = idx & 63;
        dstb[(size_t)(c0 + nn) * 1024 + (r0 + kk)] = f2bf(t[kk][nn]);
    }
}

// ---------------------------------------------------------------------------
// Layer-1 row softmax over 2048 fp32 scores, written IN PLACE as P bf16
// ---------------------------------------------------------------------------
__global__ __launch_bounds__(256) void softmax_rows(float* __restrict__ S)
{
    const int r   = blockIdx.x;                 // 0..8191 (batch*2048 + l)
    float* row    = S + (size_t)r * 2048;
    const int tid = threadIdx.x;

    const float4 a = *(const float4*)&row[tid * 8];
    const float4 b = *(const float4*)&row[tid * 8 + 4];
    float v[8] = {a.x, a.y, a.z, a.w, b.x, b.y, b.z, b.w};

    float m = v[0];
#pragma unroll
    for (int j = 1; j < 8; j++) m = fmaxf(m, v[j]);
    for (int o = 32; o; o >>= 1) m = fmaxf(m, __shfl_xor(m, o));
    __shared__ float redm[4], reds[4];
    if ((tid & 63) == 0) redm[tid >> 6] = m;
    __syncthreads();
    m = fmaxf(fmaxf(redm[0], redm[1]), fmaxf(redm[2], redm[3]));

    float e[8], s = 0.f;
#pragma unroll
    for (int j = 0; j < 8; j++) { e[j] = __expf(v[j] - m); s += e[j]; }
    for (int o = 32; o; o >>= 1) s += __shfl_xor(s, o);
    if ((tid & 63) == 0) reds[tid >> 6] = s;
    __syncthreads();
    s = reds[0] + reds[1] + reds[2] + reds[3];
    const float inv = 1.f / s;

    u16* ph = (u16*)row;          // all reads of this row completed (barriers)
    ushort4 h0, h1;
    h0.x = f2bf(e[0] * inv); h0.y = f2bf(e[1] * inv);
    h0.z = f2bf(e[2] * inv); h0.w = f2bf(e[3] * inv);
    h1.x = f2bf(e[4] * inv); h1.y = f2bf(e[5] * inv);
    h1.z = f2bf(e[6] * inv); h1.w = f2bf(e[7] * inv);
    *(ushort4*)&ph[tid * 8]     = h0;
    *(ushort4*)&ph[tid * 8 + 4] = h1;
}

// ---------------------------------------------------------------------------
// Layer-2 fused softmax + colsum stage 1: 16 rows/block.
// part[(b*128+chunk)][k] = sum over the 16 rows of softmax(S[row])[k]
// grid (4, 128), 256 thr.  No P2 write.
// ---------------------------------------------------------------------------
__global__ __launch_bounds__(256) void softmax_colsum(
    const float* __restrict__ S, float* __restrict__ part)
{
    const int b = blockIdx.x, chunk = blockIdx.y;
    const int tid = threadIdx.x;
    const float* Sb = S + (size_t)b * (2048 * 2048) + (size_t)chunk * 16 * 2048;
    __shared__ float redm[4], reds[4];
    float acc[8] = {};

    for (int r = 0; r < 16; r++) {
        const float* row = Sb + (size_t)r * 2048;
        const float4 a = *(const float4*)&row[tid * 8];
        const float4 bb = *(const float4*)&row[tid * 8 + 4];
        float v[8] = {a.x, a.y, a.z, a.w, bb.x, bb.y, bb.z, bb.w};

        float m = v[0];
#pragma unroll
        for (int j = 1; j < 8; j++) m = fmaxf(m, v[j]);
        for (int o = 32; o; o >>= 1) m = fmaxf(m, __shfl_xor(m, o));
        if ((tid & 63) == 0) redm[tid >> 6] = m;
        __syncthreads();
        m = fmaxf(fmaxf(redm[0], redm[1]), fmaxf(redm[2], redm[3]));

        float e[8], s = 0.f;
#pragma unroll
        for (int j = 0; j < 8; j++) { e[j] = __expf(v[j] - m); s += e[j]; }
        for (int o = 32; o; o >>= 1) s += __shfl_xor(s, o);
        if ((tid & 63) == 0) reds[tid >> 6] = s;
        __syncthreads();
        const float inv = 1.f / (reds[0] + reds[1] + reds[2] + reds[3]);
#pragma unroll
        for (int j = 0; j < 8; j++) acc[j] += e[j] * inv;
        __syncthreads();      // protect redm/reds reuse next row
    }

    float* p = part + ((size_t)(b * 128 + chunk)) * 2048;
#pragma unroll
    for (int j = 0; j < 8; j++) p[tid * 8 + j] = acc[j];
}

// Stage 2: csum[b][k] = sum over 128 chunks.  grid (4, 8), 256 thr
__global__ __launch_bounds__(256) void colsum_reduce(
    const float* __restrict__ part, float* __restrict__ csum)
{
    const int b = blockIdx.x, k = blockIdx.y * 256 + threadIdx.x;
    float s = 0.f;
    for (int c = 0; c < 128; c++)
        s += part[((size_t)(b * 128 + c)) * 2048 + k];
    csum[b * 2048 + k] = s;
}

// ---------------------------------------------------------------------------
// wv[d] = W_V2[d][:] . wO   grid (64), 256 thr (16 rows x 16 lanes)
// ---------------------------------------------------------------------------
__global__ __launch_bounds__(256) void wv_dot(
    const float* __restrict__ Wv2, const float* __restrict__ wO,
    float* __restrict__ wv)
{
    const int d = blockIdx.x * 16 + (threadIdx.x >> 4);
    const int lx = threadIdx.x & 15;
    const float* row = Wv2 + (size_t)d * 1024;
    float s = 0.f;
#pragma unroll
    for (int it = 0; it < 16; it++) {
        const int j = it * 64 + lx * 4;
        const float4 a = *(const float4*)&row[j];
        const float4 w = *(const float4*)&wO[j];
        s += a.x * w.x + a.y * w.y + a.z * w.z + a.w * w.w;
    }
#pragma unroll
    for (int o = 8; o; o >>= 1) s += __shfl_xor(s, o, 16);
    if (lx == 0) wv[d] = s;
}

// ---------------------------------------------------------------------------
// u[r] = H1[r][:] . wv   grid (512), 256 thr (16 rows x 16 lanes)
// ---------------------------------------------------------------------------
__global__ __launch_bounds__(256) void u_dot(
    const u16* __restrict__ H1, const float* __restrict__ wv,
    float* __restrict__ u)
{
    const int r = blockIdx.x * 16 + (threadIdx.x >> 4);
    const int lx = threadIdx.x & 15;
    const u16* row = H1 + (size_t)r * 1024;
    float s = 0.f;
#pragma unroll
    for (int it = 0; it < 8; it++) {
        const int d = it * 128 + lx * 8;
        const bf16x8 h = *(const bf16x8*)&row[d];
#pragma unroll
        for (int j = 0; j < 8; j++) s += bf2f((u16)h[j]) * wv[d + j];
    }
#pragma unroll
    for (int o = 8; o; o >>= 1) s += __shfl_xor(s, o, 16);
    if (lx == 0) u[r] = s;
}

// ---------------------------------------------------------------------------
// out[b] = sigmoid( (1/L) csum[b].u[b] + bO );  1 block, 256 thr (4b x 64)
// ---------------------------------------------------------------------------
__global__ void head_final(const float* __restrict__ csum,
                           const float* __restrict__ u,
                           const float* __restrict__ bO, float* __restrict__ out)
{
    const int b = threadIdx.x >> 6, lane = threadIdx.x & 63;
    float s = 0.f;
    for (int k = lane; k < 2048; k += 64)
        s += csum[b * 2048 + k] * u[b * 2048 + k];
    for (int o = 32; o; o >>= 1) s += __shfl_xor(s, o);
    if (lane == 0) {
        const float logit = s * (1.f / 2048.f) + bO[0];
        out[b] = 1.f / (1.f + __expf(-logit));
    }
}

// ---------------------------------------------------------------------------
extern "C" void kernel_launch(void* const* d_in, const int* in_sizes, int n_in,
                              void* d_out, int out_size, void* d_ws, size_t ws_size,
                              hipStream_t stream)
{
    const float* X   = (const float*)d_in[0];
    const float* Wq1 = (const float*)d_in[1];
    const float* Wk1 = (const float*)d_in[2];
    const float* Wv1 = (const float*)d_in[3];
    const float* Wq2 = (const float*)d_in[4];
    const float* Wk2 = (const float*)d_in[5];
    const float* Wv2 = (const float*)d_in[6];
    const float* WO  = (const float*)d_in[7];
    const float* bO  = (const float*)d_in[8];
    float* out = (float*)d_out;

    uint8_t* ws = (uint8_t*)d_ws;
    const size_t MB = 1ull << 20;
    u16* Xb   = (u16*)(ws + 0);          // X bf16; later H1 bf16
    u16* Qb   = (u16*)(ws + 32 * MB);    // Q bf16
    u16* Kb   = (u16*)(ws + 64 * MB);    // K bf16
    float* part = (float*)(ws + 80 * MB);        // 512 x 2048 fp32 (4 MB)
    float* csum = (float*)(ws + 85 * MB);        // 4 x 2048
    float* wv   = (float*)(ws + 86 * MB);        // 1024
    float* ud   = (float*)(ws + 87 * MB);        // 8192
    u16* Vtb  = (u16*)(ws + 96 * MB);    // V^T bf16 per-batch (layer 1)
    u16* Wcat = (u16*)(ws + 128 * MB);   // 5 x (1024x1024) bf16
    float* S  = (float*)(ws + 152 * MB); // 64 MB scores / P

    auto Wh = [&](int i) { return Wcat + (size_t)i * 1048576; };

    // ---- prep
    cast_bf16<<<8192, 256, 0, stream>>>(X, Xb);   // 8M elems
    transpose_cat<<<dim3(16, 16, 5), 256, 0, stream>>>(
        Wq1, Wk1, Wv1, Wq2, Wk2, Wcat);
    wv_dot<<<64, 256, 0, stream>>>(Wv2, WO, wv);

    const long long LD2 = 2048LL * 1024;   // 2M: Q/K/V batch stride
    const long long SST = 2048LL * 2048;   // 4M: S batch stride (floats)
    const long long PST = 2048LL * 4096;   // 8M: P batch stride (u16)

    // ======== layer 1 (separate projections: B = 2MB, L2-resident) ========
    gemmk<3><<<dim3(8, 64, 1), 256, 0, stream>>>(
        Xb, 0, Wh(0), 0, Qb, 0, 8192, 1024, 1024, 1024, 1024, 1024, 1.f);
    gemmk<3><<<dim3(8, 64, 1), 256, 0, stream>>>(
        Xb, 0, Wh(1), 0, Kb, 0, 8192, 1024, 1024, 1024, 1024, 1024, 1.f);
    gemmk<2><<<dim3(8, 64, 1), 256, 0, stream>>>(
        Xb, 0, Wh(2), 0, Vtb, 0, 8192, 1024, 1024, 1024, 1024, 1024, 1.f);
    gemmk<1><<<dim3(16, 16, 4), 256, 0, stream>>>(     // S = Q.K^T/32
        Qb, LD2, Kb, LD2, S, SST,
        2048, 2048, 1024, 1024, 1024, 2048, 0.03125f);
    softmax_rows<<<8192, 256, 0, stream>>>(S);
    gemmk<3><<<dim3(8, 16, 4), 256, 0, stream>>>(      // H1 = P.V -> Xb
        (u16*)S, PST, Vtb, LD2, Xb, LD2,
        2048, 1024, 2048, 4096, 2048, 1024, 1.f);

    // ======== layer 2 (no V projection; P2 never materialized) ========
    gemmk<3><<<dim3(8, 64, 1), 256, 0, stream>>>(
        Xb, 0, Wh(3), 0, Qb, 0, 8192, 1024, 1024, 1024, 1024, 1024, 1.f);
    gemmk<3><<<dim3(8, 64, 1), 256, 0, stream>>>(
        Xb, 0, Wh(4), 0, Kb, 0, 8192, 1024, 1024, 1024, 1024, 1024, 1.f);
    gemmk<1><<<dim3(16, 16, 4), 256, 0, stream>>>(
        Qb, LD2, Kb, LD2, S, SST,
        2048, 2048, 1024, 1024, 1024, 2048, 0.03125f);

    // ======== head: logit = (1/L) colsum(P2) . (H1.(W_V2.WO)) + bO ========
    softmax_colsum<<<dim3(4, 128), 256, 0, stream>>>(S, part);
    colsum_reduce<<<dim3(4, 8), 256, 0, stream>>>(part, csum);
    u_dot<<<512, 256, 0, stream>>>(Xb, wv, ud);
    head_final<<<1, 256, 0, stream>>>(csum, ud, bO, out);
}

// Round 14
// 294.901 us; speedup vs baseline: 1.6701x; 1.0980x over previous
//
#include <hip/hip_runtime.h>
#include <hip/hip_bf16.h>
#include <cstdint>

// ---------------------------------------------------------------------------
// TransformerClassifier: 2x single-head attention (N=4, L=2048, D=1024) +
// mean-pool + linear + sigmoid.
//
// v12 = v11 + score-matrix associativity:
//   S = (X Wq)(X Wk)^T = X (Wq Wk^T) X^T
//   Precompute Mt_l = Wk_l . Wq_l^T (bf16, batched z=2, 2.1 GF each), then
//   per layer: T = X . Mt^T (ONE 8192x1024x1024 GEMM) and S = T . X^T.
//   Deletes both K projections and one projection per layer (4 proj -> 2),
//   the K buffer traffic, and the Wq/Wk transposes (plain casts instead).
//   Error chain swaps {round(Q),round(K)} for {round(M),round(T)} -- same
//   number of bf16 roundings at the same relative scale.
//
// Head algebra (exact, from v10/v11):
//   pooled.WO = (1/L) colsum(P2) . (H1 . (W_V2.WO));  P2 never materialized.
//
// GEMM (unchanged, proven R9/R10/R13): 128x128 tile, BK=32, 256 thr
// (4 waves, 64x64), double-buffered LDS (16KB/buf), ONE __syncthreads per
// K-tile, global_load_lds with pre-swizzled global sources; A/B rows =
// 4x16B slots, slot = chunk ^ ((row>>1)&3)  (0 bank conflicts).
//
// ws layout (216 MB):
//   [  0MB) Xb    : X bf16; overwritten by H1 bf16        (16 MB)
//   [ 32MB) Tb    : T bf16 (per layer)                     (16 MB)
//   [ 64MB) free (old K)
//   [ 80MB) head scratch: part/csum/wv/u                   (~6 MB)
//   [ 96MB) Vtb   : V^T bf16 (per-batch [d][l], layer 1)   (16 MB)
//   [128MB) Wcat  : slots {Wq1,Wq2,Wk1,Wk2,Wv1^T,Mt1,Mt2}  (14 MB)
//   [152MB) S/P   : scores fp32 (P1 bf16 in place)         (64 MB)
// ---------------------------------------------------------------------------

#define DEVFN __device__ __forceinline__

typedef __attribute__((ext_vector_type(8))) short bf16x8;
typedef __attribute__((ext_vector_type(4))) float f32x4;
typedef unsigned short u16;

DEVFN u16 f2bf(float f) {               // round-to-nearest-even bf16 (finite)
    uint32_t x = __float_as_uint(f);
    x += 0x7fffu + ((x >> 16) & 1u);
    return (u16)(x >> 16);
}
DEVFN float bf2f(u16 u) { return __uint_as_float(((uint32_t)u) << 16); }

DEVFN void gload_lds16(const void* g, void* l) {
    __builtin_amdgcn_global_load_lds(
        (const __attribute__((address_space(1))) void*)g,
        (__attribute__((address_space(3))) void*)l, 16, 0, 0);
}

#define MFMA16 __builtin_amdgcn_mfma_f32_16x16x32_bf16

// ---------------------------------------------------------------------------
// bf16 GEMM:  C = scale * (A . B^T)
//   A : M x K row-major bf16 (lda);  B : N x K row-major bf16 (ldb)
// Tile 128x128, BK=32.  grid (N/128, M/128, Z), total blocks % 8 == 0.
// EPI: 1 = fp32 row-major;  2 = V^T bf16 per-batch;  3 = bf16 row-major
// ---------------------------------------------------------------------------
template<int EPI>
__global__ __launch_bounds__(256, 4) void gemmk(
    const u16* __restrict__ A, long long aStride,
    const u16* __restrict__ B, long long bStride,
    void* __restrict__ out0, long long cStride,
    int M, int N, int K, int lda, int ldb, int ldc, float scale)
{
    constexpr int ASEC  = 128 * 32;          // u16 per buffer, A section
    constexpr int BUFSZ = ASEC + 128 * 32;   // + B section
    constexpr int NU    = 4;                 // stage units (A:2, B:2)

    __shared__ __align__(16) u16 L[2 * BUFSZ];
    const int tid  = threadIdx.x;
    const int wave = tid >> 6, lane = tid & 63;

    // bijective XCD-aware block swizzle (all launches have nwg % 8 == 0)
    const int gx = gridDim.x, gy = gridDim.y;
    const int nwg = gx * gy * gridDim.z;
    int flat = (blockIdx.z * gy + blockIdx.y) * gx + blockIdx.x;
    flat = (flat & 7) * (nwg >> 3) + (flat >> 3);
    const int bx = flat % gx, by = (flat / gx) % gy, bz = flat / (gx * gy);

    const u16* pA = A + (size_t)bz * aStride;
    const u16* pB = B + (size_t)bz * bStride;
    const int m0 = by * 128, n0 = bx * 128;

    // ---- staging units: each = 2048 u16 (256 thr x 16B), linear LDS dest;
    // 4 slots/row, stored chunk = slot ^ ((row>>1)&3)  (pre-swizzled source)
    const u16* src[NU];
    int dst[NU];
#pragma unroll
    for (int q = 0; q < 2; q++) {
        const int s = q * 256 + tid, row = s >> 2, c = (s & 3) ^ ((row >> 1) & 3);
        src[q]     = pA + (size_t)(m0 + row) * lda + c * 8;
        dst[q]     = q * 2048 + wave * 512;
        src[2 + q] = pB + (size_t)(n0 + row) * ldb + c * 8;
        dst[2 + q] = ASEC + q * 2048 + wave * 512;
    }

    // ---- fragment geometry (16x16 frags; wave = 64x64 quadrant)
    const int fr = lane & 15, ch = lane >> 4;
    const int wr = (wave >> 1) * 64, wc = (wave & 1) * 64;

    const int NT = K >> 5;

    // ---- prologue: stage tile 0 into buffer 0
#pragma unroll
    for (int u = 0; u < NU; u++) { gload_lds16(src[u], &L[dst[u]]); src[u] += 32; }
    __syncthreads();

    f32x4 acc[4][4] = {};
    int cur = 0;

    for (int kt = 0; kt < NT; ++kt) {
        const int cOff = cur * BUFSZ;
        const int sOff = BUFSZ - cOff;
        if (kt + 1 < NT) {
#pragma unroll
            for (int u = 0; u < NU; u++) { gload_lds16(src[u], &L[sOff + dst[u]]); src[u] += 32; }
        }

        bf16x8 ah[4], bh[4];
#pragma unroll
        for (int i = 0; i < 4; i++) {
            const int r = wr + i * 16 + fr;
            ah[i] = *(const bf16x8*)&L[cOff + r * 32 + ((ch ^ ((r >> 1) & 3)) << 3)];
        }
#pragma unroll
        for (int j = 0; j < 4; j++) {
            const int r = wc + j * 16 + fr;
            bh[j] = *(const bf16x8*)&L[cOff + ASEC + r * 32 + ((ch ^ ((r >> 1) & 3)) << 3)];
        }

#pragma unroll
        for (int i = 0; i < 4; i++)
#pragma unroll
            for (int j = 0; j < 4; j++)
                acc[i][j] = MFMA16(ah[i], bh[j], acc[i][j], 0, 0, 0);

        __syncthreads();     // drains vmcnt (staging) + lgkm; swap buffers
        cur ^= 1;
    }

    // ---- epilogue: C/D layout col = lane&15, row = (lane>>4)*4 + r
#pragma unroll
    for (int i = 0; i < 4; i++)
#pragma unroll
        for (int j = 0; j < 4; j++)
#pragma unroll
            for (int r = 0; r < 4; r++) {
                const int row = m0 + wr + i * 16 + (lane >> 4) * 4 + r;
                const int col = n0 + wc + j * 16 + (lane & 15);
                const float v = acc[i][j][r] * scale;
                if constexpr (EPI == 1) {
                    ((float*)out0)[(size_t)bz * cStride + (size_t)row * ldc + col] = v;
                } else if constexpr (EPI == 2) {  // V^T bf16, per-batch
                    const int b = row >> 11, ll = row & 2047;
                    ((u16*)out0)[(size_t)b * (2048 * 1024) + (size_t)col * 2048 + ll] = f2bf(v);
                } else {                          // EPI == 3: bf16 row-major
                    ((u16*)out0)[(size_t)bz * cStride + (size_t)row * ldc + col] = f2bf(v);
                }
            }
}

// ---------------------------------------------------------------------------
__global__ __launch_bounds__(256) void cast_bf16(
    const float* __restrict__ x, u16* __restrict__ o)
{
    const size_t i = ((size_t)blockIdx.x * 256 + threadIdx.x) * 4;
    const float4 v = *(const float4*)&x[i];
    ushort4 h;
    h.x = f2bf(v.x); h.y = f2bf(v.y); h.z = f2bf(v.z); h.w = f2bf(v.w);
    *(ushort4*)&o[i] = h;
}

// ---------------------------------------------------------------------------
// Batched cast of 4 weight matrices (non-transposed) into Wcat slots 0..3.
// grid (1024, 4), 256 thr, 4 elems/thr
// ---------------------------------------------------------------------------
__global__ __launch_bounds__(256) void cast4_bf16(
    const float* __restrict__ W0, const float* __restrict__ W1,
    const float* __restrict__ W2, const float* __restrict__ W3,
    u16* __restrict__ Wcat)
{
    const int w = blockIdx.y;
    const float* W = (w == 0) ? W0 : (w == 1) ? W1 : (w == 2) ? W2 : W3;
    u16* o = Wcat + (size_t)w * 1048576;
    const size_t i = ((size_t)blockIdx.x * 256 + threadIdx.x) * 4;
    const float4 v = *(const float4*)&W[i];
    ushort4 h;
    h.x = f2bf(v.x); h.y = f2bf(v.y); h.z = f2bf(v.z); h.w = f2bf(v.w);
    *(ushort4*)&o[i] = h;
}

// ---------------------------------------------------------------------------
// Wv1 (1024x1024 fp32 [d][k]) -> W^T bf16 ([k][d]) into its slot
// ---------------------------------------------------------------------------
__global__ __launch_bounds__(256) void transpose_w(
    const float* __restrict__ W, u16* __restrict__ thi)
{
    __shared__ float t[64][65];
    const int tid = threadIdx.x;
    const int r0 = blockIdx.y * 64, c0 = blockIdx.x * 64;
#pragma unroll
    for (int it = 0; it < 16; it++) {
        const int idx = it * 256 + tid, rr = idx >> 6, cc = idx & 63;
        t[rr][cc] = W[(size_t)(r0 + rr) * 1024 + (c0 + cc)];
    }
    __syncthreads();
#pragma unroll
    for (int it = 0; it < 16; it++) {
        const int idx = it * 256 + tid, nn = idx >> 6, kk = idx & 63;
        thi[(size_t)(c0 + nn) * 1024 + (r0 + kk)] = f2bf(t[kk][nn]);
    }
}

// ---------------------------------------------------------------------------
// Layer-1 row softmax over 2048 fp32 scores, written IN PLACE as P bf16
// ---------------------------------------------------------------------------
__global__ __launch_bounds__(256) void softmax_rows(float* __restrict__ S)
{
    const int r   = blockIdx.x;                 // 0..8191 (batch*2048 + l)
    float* row    = S + (size_t)r * 2048;
    const int tid = threadIdx.x;

    const float4 a = *(const float4*)&row[tid * 8];
    const float4 b = *(const float4*)&row[tid * 8 + 4];
    float v[8] = {a.x, a.y, a.z, a.w, b.x, b.y, b.z, b.w};

    float m = v[0];
#pragma unroll
    for (int j = 1; j < 8; j++) m = fmaxf(m, v[j]);
    for (int o = 32; o; o >>= 1) m = fmaxf(m, __shfl_xor(m, o));
    __shared__ float redm[4], reds[4];
    if ((tid & 63) == 0) redm[tid >> 6] = m;
    __syncthreads();
    m = fmaxf(fmaxf(redm[0], redm[1]), fmaxf(redm[2], redm[3]));

    float e[8], s = 0.f;
#pragma unroll
    for (int j = 0; j < 8; j++) { e[j] = __expf(v[j] - m); s += e[j]; }
    for (int o = 32; o; o >>= 1) s += __shfl_xor(s, o);
    if ((tid & 63) == 0) reds[tid >> 6] = s;
    __syncthreads();
    s = reds[0] + reds[1] + reds[2] + reds[3];
    const float inv = 1.f / s;

    u16* ph = (u16*)row;          // all reads of this row completed (barriers)
    ushort4 h0, h1;
    h0.x = f2bf(e[0] * inv); h0.y = f2bf(e[1] * inv);
    h0.z = f2bf(e[2] * inv); h0.w = f2bf(e[3] * inv);
    h1.x = f2bf(e[4] * inv); h1.y = f2bf(e[5] * inv);
    h1.z = f2bf(e[6] * inv); h1.w = f2bf(e[7] * inv);
    *(ushort4*)&ph[tid * 8]     = h0;
    *(ushort4*)&ph[tid * 8 + 4] = h1;
}

// ---------------------------------------------------------------------------
// Layer-2 fused softmax + colsum stage 1: 16 rows/block.
// part[(b*128+chunk)][k] = sum over the 16 rows of softmax(S[row])[k]
// grid (4, 128), 256 thr.  No P2 write.
// ---------------------------------------------------------------------------
__global__ __launch_bounds__(256) void softmax_colsum(
    const float* __restrict__ S, float* __restrict__ part)
{
    const int b = blockIdx.x, chunk = blockIdx.y;
    const int tid = threadIdx.x;
    const float* Sb = S + (size_t)b * (2048 * 2048) + (size_t)chunk * 16 * 2048;
    __shared__ float redm[4], reds[4];
    float acc[8] = {};

    for (int r = 0; r < 16; r++) {
        const float* row = Sb + (size_t)r * 2048;
        const float4 a = *(const float4*)&row[tid * 8];
        const float4 bb = *(const float4*)&row[tid * 8 + 4];
        float v[8] = {a.x, a.y, a.z, a.w, bb.x, bb.y, bb.z, bb.w};

        float m = v[0];
#pragma unroll
        for (int j = 1; j < 8; j++) m = fmaxf(m, v[j]);
        for (int o = 32; o; o >>= 1) m = fmaxf(m, __shfl_xor(m, o));
        if ((tid & 63) == 0) redm[tid >> 6] = m;
        __syncthreads();
        m = fmaxf(fmaxf(redm[0], redm[1]), fmaxf(redm[2], redm[3]));

        float e[8], s = 0.f;
#pragma unroll
        for (int j = 0; j < 8; j++) { e[j] = __expf(v[j] - m); s += e[j]; }
        for (int o = 32; o; o >>= 1) s += __shfl_xor(s, o);
        if ((tid & 63) == 0) reds[tid >> 6] = s;
        __syncthreads();
        const float inv = 1.f / (reds[0] + reds[1] + reds[2] + reds[3]);
#pragma unroll
        for (int j = 0; j < 8; j++) acc[j] += e[j] * inv;
        __syncthreads();      // protect redm/reds reuse next row
    }

    float* p = part + ((size_t)(b * 128 + chunk)) * 2048;
#pragma unroll
    for (int j = 0; j < 8; j++) p[tid * 8 + j] = acc[j];
}

// Stage 2: csum[b][k] = sum over 128 chunks.  grid (4, 8), 256 thr
__global__ __launch_bounds__(256) void colsum_reduce(
    const float* __restrict__ part, float* __restrict__ csum)
{
    const int b = blockIdx.x, k = blockIdx.y * 256 + threadIdx.x;
    float s = 0.f;
    for (int c = 0; c < 128; c++)
        s += part[((size_t)(b * 128 + c)) * 2048 + k];
    csum[b * 2048 + k] = s;
}

// ---------------------------------------------------------------------------
// wv[d] = W_V2[d][:] . wO   grid (64), 256 thr (16 rows x 16 lanes)
// ---------------------------------------------------------------------------
__global__ __launch_bounds__(256) void wv_dot(
    const float* __restrict__ Wv2, const float* __restrict__ wO,
    float* __restrict__ wv)
{
    const int d = blockIdx.x * 16 + (threadIdx.x >> 4);
    const int lx = threadIdx.x & 15;
    const float* row = Wv2 + (size_t)d * 1024;
    float s = 0.f;
#pragma unroll
    for (int it = 0; it < 16; it++) {
        const int j = it * 64 + lx * 4;
        const float4 a = *(const float4*)&row[j];
        const float4 w = *(const float4*)&wO[j];
        s += a.x * w.x + a.y * w.y + a.z * w.z + a.w * w.w;
    }
#pragma unroll
    for (int o = 8; o; o >>= 1) s += __shfl_xor(s, o, 16);
    if (lx == 0) wv[d] = s;
}

// ---------------------------------------------------------------------------
// u[r] = H1[r][:] . wv   grid (512), 256 thr (16 rows x 16 lanes)
// ---------------------------------------------------------------------------
__global__ __launch_bounds__(256) void u_dot(
    const u16* __restrict__ H1, const float* __restrict__ wv,
    float* __restrict__ u)
{
    const int r = blockIdx.x * 16 + (threadIdx.x >> 4);
    const int lx = threadIdx.x & 15;
    const u16* row = H1 + (size_t)r * 1024;
    float s = 0.f;
#pragma unroll
    for (int it = 0; it < 8; it++) {
        const int d = it * 128 + lx * 8;
        const bf16x8 h = *(const bf16x8*)&row[d];
#pragma unroll
        for (int j = 0; j < 8; j++) s += bf2f((u16)h[j]) * wv[d + j];
    }
#pragma unroll
    for (int o = 8; o; o >>= 1) s += __shfl_xor(s, o, 16);
    if (lx == 0) u[r] = s;
}

// ---------------------------------------------------------------------------
// out[b] = sigmoid( (1/L) csum[b].u[b] + bO );  1 block, 256 thr (4b x 64)
// ---------------------------------------------------------------------------
__global__ void head_final(const float* __restrict__ csum,
                           const float* __restrict__ u,
                           const float* __restrict__ bO, float* __restrict__ out)
{
    const int b = threadIdx.x >> 6, lane = threadIdx.x & 63;
    float s = 0.f;
    for (int k = lane; k < 2048; k += 64)
        s += csum[b * 2048 + k] * u[b * 2048 + k];
    for (int o = 32; o; o >>= 1) s += __shfl_xor(s, o);
    if (lane == 0) {
        const float logit = s * (1.f / 2048.f) + bO[0];
        out[b] = 1.f / (1.f + __expf(-logit));
    }
}

// ---------------------------------------------------------------------------
extern "C" void kernel_launch(void* const* d_in, const int* in_sizes, int n_in,
                              void* d_out, int out_size, void* d_ws, size_t ws_size,
                              hipStream_t stream)
{
    const float* X   = (const float*)d_in[0];
    const float* Wq1 = (const float*)d_in[1];
    const float* Wk1 = (const float*)d_in[2];
    const float* Wv1 = (const float*)d_in[3];
    const float* Wq2 = (const float*)d_in[4];
    const float* Wk2 = (const float*)d_in[5];
    const float* Wv2 = (const float*)d_in[6];
    const float* WO  = (const float*)d_in[7];
    const float* bO  = (const float*)d_in[8];
    float* out = (float*)d_out;

    uint8_t* ws = (uint8_t*)d_ws;
    const size_t MB = 1ull << 20;
    u16* Xb   = (u16*)(ws + 0);          // X bf16; later H1 bf16
    u16* Tb   = (u16*)(ws + 32 * MB);    // T bf16 (per layer)
    float* part = (float*)(ws + 80 * MB);        // 512 x 2048 fp32 (4 MB)
    float* csum = (float*)(ws + 85 * MB);        // 4 x 2048
    float* wv   = (float*)(ws + 86 * MB);        // 1024
    float* ud   = (float*)(ws + 87 * MB);        // 8192
    u16* Vtb  = (u16*)(ws + 96 * MB);    // V^T bf16 per-batch (layer 1)
    u16* Wcat = (u16*)(ws + 128 * MB);   // slots below (1M u16 each)
    float* S  = (float*)(ws + 152 * MB); // 64 MB scores / P

    // Wcat slots: 0 Wq1b, 1 Wq2b, 2 Wk1b, 3 Wk2b, 4 Wv1^T, 5 Mt1, 6 Mt2
    auto Wslot = [&](int i) { return Wcat + (size_t)i * 1048576; };

    // ---- prep
    cast_bf16<<<8192, 256, 0, stream>>>(X, Xb);   // 8M elems
    cast4_bf16<<<dim3(1024, 4), 256, 0, stream>>>(Wq1, Wq2, Wk1, Wk2, Wcat);
    transpose_w<<<dim3(16, 16), 256, 0, stream>>>(Wv1, Wslot(4));
    wv_dot<<<64, 256, 0, stream>>>(Wv2, WO, wv);
    // Mt_l = Wk_l . Wq_l^T  (batched z=2): A slots 2..3, B slots 0..1
    gemmk<3><<<dim3(8, 8, 2), 256, 0, stream>>>(
        Wslot(2), 1048576, Wslot(0), 1048576, Wslot(5), 1048576,
        1024, 1024, 1024, 1024, 1024, 1024, 1.f);

    const long long LD2 = 2048LL * 1024;   // 2M: batch stride (u16)
    const long long SST = 2048LL * 2048;   // 4M: S batch stride (floats)
    const long long PST = 2048LL * 4096;   // 8M: P batch stride (u16)

    // ======== layer 1 ========
    gemmk<3><<<dim3(8, 64, 1), 256, 0, stream>>>(      // T1 = X.Mt1^T
        Xb, 0, Wslot(5), 0, Tb, 0, 8192, 1024, 1024, 1024, 1024, 1024, 1.f);
    gemmk<2><<<dim3(8, 64, 1), 256, 0, stream>>>(      // V1 proj -> V^T
        Xb, 0, Wslot(4), 0, Vtb, 0, 8192, 1024, 1024, 1024, 1024, 1024, 1.f);
    gemmk<1><<<dim3(16, 16, 4), 256, 0, stream>>>(     // S = T1.X^T / 32
        Tb, LD2, Xb, LD2, S, SST,
        2048, 2048, 1024, 1024, 1024, 2048, 0.03125f);
    softmax_rows<<<8192, 256, 0, stream>>>(S);
    gemmk<3><<<dim3(8, 16, 4), 256, 0, stream>>>(      // H1 = P.V -> Xb
        (u16*)S, PST, Vtb, LD2, Xb, LD2,
        2048, 1024, 2048, 4096, 2048, 1024, 1.f);

    // ======== layer 2 (no V projection; P2 never materialized) ========
    gemmk<3><<<dim3(8, 64, 1), 256, 0, stream>>>(      // T2 = H1.Mt2^T
        Xb, 0, Wslot(6), 0, Tb, 0, 8192, 1024, 1024, 1024, 1024, 1024, 1.f);
    gemmk<1><<<dim3(16, 16, 4), 256, 0, stream>>>(     // S = T2.H1^T / 32
        Tb, LD2, Xb, LD2, S, SST,
        2048, 2048, 1024, 1024, 1024, 2048, 0.03125f);

    // ======== head: logit = (1/L) colsum(P2) . (H1.(W_V2.WO)) + bO ========
    softmax_colsum<<<dim3(4, 128), 256, 0, stream>>>(S, part);
    colsum_reduce<<<dim3(4, 8), 256, 0, stream>>>(part, csum);
    u_dot<<<512, 256, 0, stream>>>(Xb, wv, ud);
    head_final<<<1, 256, 0, stream>>>(csum, ud, bO, out);
}